// Round 16
// baseline (142.466 us; speedup 1.0000x reference)
//
#include <hip/hip_runtime.h>
#include <hip/hip_bf16.h>

#define N_NODES 50000
#define N_EDGES 800000
#define IN_DIM  64
#define HID_DIM 128
#define OUT_DIM 32
#define ELLW    64    // max supported degree; P(max_deg>64) ~ 1e-13 for this graph

#define NRANGE   8
#define RNG      (N_NODES / NRANGE)                      // 6250
#define FILL_CH  2048
#define FILL_NJ  ((N_EDGES + FILL_CH - 1) / FILL_CH)     // 391

#define CAST_BLKS 3125   // 800000 float4 / 256
#define PW1_BLKS  32     // 64*128/256
#define PW2_BLKS  64     // 128*128/256
#define PWO_BLKS  16     // 128*32/256
#define ZERO_BLKS 49     // 49*1024 >= 50000 ints

typedef short bh8_t  __attribute__((ext_vector_type(8)));   // 8 bf16 (4 VGPRs)
typedef float fx4_t  __attribute__((ext_vector_type(4)));   // MFMA acc
// ext_vector types for nontemporal builtins (HIP_vector_type structs rejected)
typedef float          fv4  __attribute__((ext_vector_type(4)));
typedef unsigned short usv4 __attribute__((ext_vector_type(4)));
typedef int            iv4  __attribute__((ext_vector_type(4)));

// bf16 helpers (raw-bit, header-version independent)
__device__ inline float bflo(unsigned int u) {
    union { unsigned int i; float f; } c; c.i = u << 16; return c.f;
}
__device__ inline float bfhi(unsigned int u) {
    union { unsigned int i; float f; } c; c.i = u & 0xffff0000u; return c.f;
}
__device__ inline unsigned short f2bf(float f) {   // round-to-nearest-even
    union { float f; unsigned int i; } c; c.f = f;
    unsigned int u = c.i;
    u += 0x7fffu + ((u >> 16) & 1u);
    return (unsigned short)(u >> 16);
}
__device__ inline unsigned int pack2(float a, float b) {
    return (unsigned int)f2bf(a) | ((unsigned int)f2bf(b) << 16);
}
__device__ inline void acc_u4(float* a, uint4 u) {
    a[0] += bflo(u.x); a[1] += bfhi(u.x);
    a[2] += bflo(u.y); a[3] += bfhi(u.y);
    a[4] += bflo(u.z); a[5] += bfhi(u.z);
    a[6] += bflo(u.w); a[7] += bfhi(u.w);
}

template <int K, int M>
__device__ inline void packw_one(const float* __restrict__ W,
                                 unsigned short* __restrict__ Wp, int f) {
    const int k = f / M, m = f % M;
    Wp[((k >> 3) * M + m) * 8 + (k & 7)] = f2bf(W[f]);
}

// ---------------------------------------------------------------------------
// K0: prep — cast x -> bf16 (nt-load x, nt-store xb: pure streaming, keep L2
//     clean), pack W1/W2/Wout, zero cnt.  Separate from the scatter (R9's
//     fused k_pe polluted the scatter's L2 residency -> WRITE 37.8MB).
// ---------------------------------------------------------------------------
__global__ void k_prep(const float* __restrict__ x, unsigned short* __restrict__ xb,
                       const float* __restrict__ W1, unsigned short* __restrict__ wp1,
                       const float* __restrict__ W2, unsigned short* __restrict__ wp2,
                       const float* __restrict__ Wout, unsigned short* __restrict__ wpo,
                       int* __restrict__ cnt) {
    const int bid = blockIdx.x;
    if (bid < CAST_BLKS) {
        const int i = bid * 256 + threadIdx.x;            // exactly 800000 float4s
        fv4 v = __builtin_nontemporal_load(reinterpret_cast<const fv4*>(x) + i);
        usv4 o;
        o.x = f2bf(v.x); o.y = f2bf(v.y); o.z = f2bf(v.z); o.w = f2bf(v.w);
        __builtin_nontemporal_store(o, reinterpret_cast<usv4*>(xb) + i);
    } else if (bid < CAST_BLKS + PW1_BLKS) {
        packw_one<IN_DIM, HID_DIM>(W1, wp1, (bid - CAST_BLKS) * 256 + threadIdx.x);
    } else if (bid < CAST_BLKS + PW1_BLKS + PW2_BLKS) {
        packw_one<HID_DIM, HID_DIM>(W2, wp2, (bid - CAST_BLKS - PW1_BLKS) * 256 + threadIdx.x);
    } else if (bid < CAST_BLKS + PW1_BLKS + PW2_BLKS + PWO_BLKS) {
        packw_one<HID_DIM, OUT_DIM>(Wout, wpo,
                                    (bid - CAST_BLKS - PW1_BLKS - PW2_BLKS) * 256 + threadIdx.x);
    } else {
        const int zb = bid - (CAST_BLKS + PW1_BLKS + PW2_BLKS + PWO_BLKS);
#pragma unroll
        for (int k2 = 0; k2 < 4; ++k2) {
            const int i = zb * 1024 + k2 * 256 + threadIdx.x;
            if (i < N_NODES) cnt[i] = 0;
        }
    }
}

// ---------------------------------------------------------------------------
// K1: single-pass ELL build, dst-range x XCD partitioned (R7 champion shape:
//     2048-edge chunks).  r = blockIdx&7 owns [r*6250,(r+1)*6250) and
//     round-robins to one XCD.  src/dst reads NONTEMPORAL — the ~6MB/XCD
//     edge stream was evicting the 1.6MB ELL slice + cnt from the 4MB L2
//     between a node's ~16 temporally-spread writes (the write amplification
//     seen as 28-50MB WRITE_SIZE in R9/R11).  nt keeps scatter targets
//     resident so lines coalesce before writeback.
// ---------------------------------------------------------------------------
__global__ __launch_bounds__(256) void k_ell(const int* __restrict__ src,
                                             const int* __restrict__ dst,
                                             int* __restrict__ cnt,
                                             int* __restrict__ ell) {
    const int r    = blockIdx.x & (NRANGE - 1);
    const int j    = blockIdx.x >> 3;
    const int lo   = r * RNG;
    const int base = j * FILL_CH;
#pragma unroll
    for (int i = 0; i < FILL_CH / 256; ++i) {
        const int e = base + i * 256 + threadIdx.x;
        if (e < N_EDGES) {
            const int d = __builtin_nontemporal_load(dst + e);
            if ((unsigned)(d - lo) < (unsigned)RNG) {
                const int s = __builtin_nontemporal_load(src + e);
                const int p = atomicAdd(&cnt[d], 1);
                if (p < ELLW) ell[(size_t)d * ELLW + p] = s;
            }
        }
    }
}

// ---------------------------------------------------------------------------
// K2: layer-1 aggregation (64-dim) over ELL.  8 lanes/node x uint4
//     (32 nodes/block) — same bytes per row, 2x nodes in flight per wave.
//     ELL index reads nontemporal (streamed once; keep L2 for the xb table).
// ---------------------------------------------------------------------------
__global__ __launch_bounds__(256) void k_agg1(const unsigned short* __restrict__ Xb,
                                              const int* __restrict__ ell,
                                              const int* __restrict__ cnt,
                                              unsigned short* __restrict__ Mb) {
    const int gid  = threadIdx.x >> 3;          // 0..31
    const int lane = threadIdx.x & 7;
    const int node = blockIdx.x * 32 + gid;
    if (node >= N_NODES) return;
    const int c = min(cnt[node], ELLW);
    const float r = (c > 0) ? 1.0f / (float)c : 0.0f;
    const int* er = ell + (size_t)node * ELLW;
    const unsigned short* base = Xb + lane * 8;

    float a0[8], a1[8];
#pragma unroll
    for (int v = 0; v < 8; ++v) { a0[v] = 0.f; a1[v] = 0.f; }

    int j = 0;
    for (; j + 8 <= c; j += 8) {
        const iv4 e03 = __builtin_nontemporal_load(reinterpret_cast<const iv4*>(er + j));
        const iv4 e47 = __builtin_nontemporal_load(reinterpret_cast<const iv4*>(er + j + 4));
        uint4 u0 = *reinterpret_cast<const uint4*>(base + (size_t)e03.x * IN_DIM);
        uint4 u1 = *reinterpret_cast<const uint4*>(base + (size_t)e03.y * IN_DIM);
        uint4 u2 = *reinterpret_cast<const uint4*>(base + (size_t)e03.z * IN_DIM);
        uint4 u3 = *reinterpret_cast<const uint4*>(base + (size_t)e03.w * IN_DIM);
        uint4 u4 = *reinterpret_cast<const uint4*>(base + (size_t)e47.x * IN_DIM);
        uint4 u5 = *reinterpret_cast<const uint4*>(base + (size_t)e47.y * IN_DIM);
        uint4 u6 = *reinterpret_cast<const uint4*>(base + (size_t)e47.z * IN_DIM);
        uint4 u7 = *reinterpret_cast<const uint4*>(base + (size_t)e47.w * IN_DIM);
        acc_u4(a0, u0); acc_u4(a1, u1); acc_u4(a0, u2); acc_u4(a1, u3);
        acc_u4(a0, u4); acc_u4(a1, u5); acc_u4(a0, u6); acc_u4(a1, u7);
    }
    for (; j + 4 <= c; j += 4) {
        const iv4 e4 = __builtin_nontemporal_load(reinterpret_cast<const iv4*>(er + j));
        uint4 u0 = *reinterpret_cast<const uint4*>(base + (size_t)e4.x * IN_DIM);
        uint4 u1 = *reinterpret_cast<const uint4*>(base + (size_t)e4.y * IN_DIM);
        uint4 u2 = *reinterpret_cast<const uint4*>(base + (size_t)e4.z * IN_DIM);
        uint4 u3 = *reinterpret_cast<const uint4*>(base + (size_t)e4.w * IN_DIM);
        acc_u4(a0, u0); acc_u4(a1, u1); acc_u4(a0, u2); acc_u4(a1, u3);
    }
    for (; j < c; ++j) {
        const int s = __builtin_nontemporal_load(er + j);
        uint4 u = *reinterpret_cast<const uint4*>(base + (size_t)s * IN_DIM);
        acc_u4(a0, u);
    }

    uint4 o;
    o.x = pack2((a0[0] + a1[0]) * r, (a0[1] + a1[1]) * r);
    o.y = pack2((a0[2] + a1[2]) * r, (a0[3] + a1[3]) * r);
    o.z = pack2((a0[4] + a1[4]) * r, (a0[5] + a1[5]) * r);
    o.w = pack2((a0[6] + a1[6]) * r, (a0[7] + a1[7]) * r);
    *reinterpret_cast<uint4*>(Mb + (size_t)node * IN_DIM + lane * 8) = o;
}

// ---------------------------------------------------------------------------
// K3: layer-1 MFMA GEMM.  h1b = bf16(relu(m1b @ wp1 + b1)), masked by cnt.
//     A-row loads nontemporal (each row read exactly once).
// ---------------------------------------------------------------------------
__global__ __launch_bounds__(256) void k_mgemm1(const unsigned short* __restrict__ A,
                                                const unsigned short* __restrict__ Wpg,
                                                const float* __restrict__ b1,
                                                const int* __restrict__ cnt,
                                                unsigned short* __restrict__ h1b) {
    __shared__ unsigned short Wp[IN_DIM * HID_DIM];   // 16 KB
    const int tid = threadIdx.x;
#pragma unroll
    for (int f = tid; f < IN_DIM * HID_DIM / 8; f += 256)
        reinterpret_cast<uint4*>(Wp)[f] = reinterpret_cast<const uint4*>(Wpg)[f];
    __syncthreads();

    const int w  = tid >> 6;
    const int l  = tid & 63;
    const int lr = l & 15;
    const int lg = l >> 4;
    const int row = blockIdx.x * 64 + w * 16 + lr;
    const bool rok = row < N_NODES;
    const unsigned short* Arow = A + (size_t)row * IN_DIM;

    fx4_t acc[8];
#pragma unroll
    for (int ct = 0; ct < 8; ++ct) acc[ct] = (fx4_t){0.f, 0.f, 0.f, 0.f};

#pragma unroll
    for (int kc = 0; kc < IN_DIM; kc += 32) {
        bh8_t af = {};
        if (rok) af = __builtin_nontemporal_load(
            reinterpret_cast<const bh8_t*>(Arow + kc + lg * 8));
#pragma unroll
        for (int ct = 0; ct < 8; ++ct) {
            const bh8_t bf = *reinterpret_cast<const bh8_t*>(
                &Wp[(((kc >> 3) + lg) * HID_DIM + ct * 16 + lr) * 8]);
            acc[ct] = __builtin_amdgcn_mfma_f32_16x16x32_bf16(af, bf, acc[ct], 0, 0, 0);
        }
    }

    const int orow0 = blockIdx.x * 64 + w * 16 + lg * 4;
    bool on[4];
#pragma unroll
    for (int r = 0; r < 4; ++r)
        on[r] = (orow0 + r < N_NODES) && (cnt[orow0 + r] > 0);

#pragma unroll
    for (int ct = 0; ct < 8; ++ct) {
        const int m = ct * 16 + lr;
        const float bm = b1[m];
#pragma unroll
        for (int r = 0; r < 4; ++r) {
            const int n = orow0 + r;
            if (n < N_NODES) {
                float v = on[r] ? fmaxf(acc[ct][r] + bm, 0.f) : 0.f;
                h1b[(size_t)n * HID_DIM + m] = f2bf(v);
            }
        }
    }
}

// ---------------------------------------------------------------------------
// K4: layer-2 aggregation (128-dim) over ELL; 16 lanes/node, 8-edge pipeline.
//     ELL index reads nontemporal (keep L2 for the h1b gather table).
// ---------------------------------------------------------------------------
__global__ __launch_bounds__(256) void k_agg2(const unsigned short* __restrict__ Xb,
                                              const int* __restrict__ ell,
                                              const int* __restrict__ cnt,
                                              unsigned short* __restrict__ Mb) {
    const int gid  = threadIdx.x >> 4;
    const int lane = threadIdx.x & 15;
    const int node = blockIdx.x * 16 + gid;     // grid 3125*16 = 50000 exact
    const int c = min(cnt[node], ELLW);
    const float r = (c > 0) ? 1.0f / (float)c : 0.0f;
    const int* er = ell + (size_t)node * ELLW;
    const unsigned short* base = Xb + lane * 8;

    float a0[8], a1[8];
#pragma unroll
    for (int v = 0; v < 8; ++v) { a0[v] = 0.f; a1[v] = 0.f; }

    int j = 0;
    for (; j + 8 <= c; j += 8) {
        const iv4 e03 = __builtin_nontemporal_load(reinterpret_cast<const iv4*>(er + j));
        const iv4 e47 = __builtin_nontemporal_load(reinterpret_cast<const iv4*>(er + j + 4));
        uint4 u0 = *reinterpret_cast<const uint4*>(base + (size_t)e03.x * HID_DIM);
        uint4 u1 = *reinterpret_cast<const uint4*>(base + (size_t)e03.y * HID_DIM);
        uint4 u2 = *reinterpret_cast<const uint4*>(base + (size_t)e03.z * HID_DIM);
        uint4 u3 = *reinterpret_cast<const uint4*>(base + (size_t)e03.w * HID_DIM);
        uint4 u4 = *reinterpret_cast<const uint4*>(base + (size_t)e47.x * HID_DIM);
        uint4 u5 = *reinterpret_cast<const uint4*>(base + (size_t)e47.y * HID_DIM);
        uint4 u6 = *reinterpret_cast<const uint4*>(base + (size_t)e47.z * HID_DIM);
        uint4 u7 = *reinterpret_cast<const uint4*>(base + (size_t)e47.w * HID_DIM);
        acc_u4(a0, u0); acc_u4(a1, u1); acc_u4(a0, u2); acc_u4(a1, u3);
        acc_u4(a0, u4); acc_u4(a1, u5); acc_u4(a0, u6); acc_u4(a1, u7);
    }
    for (; j + 4 <= c; j += 4) {
        const iv4 e4 = __builtin_nontemporal_load(reinterpret_cast<const iv4*>(er + j));
        uint4 u0 = *reinterpret_cast<const uint4*>(base + (size_t)e4.x * HID_DIM);
        uint4 u1 = *reinterpret_cast<const uint4*>(base + (size_t)e4.y * HID_DIM);
        uint4 u2 = *reinterpret_cast<const uint4*>(base + (size_t)e4.z * HID_DIM);
        uint4 u3 = *reinterpret_cast<const uint4*>(base + (size_t)e4.w * HID_DIM);
        acc_u4(a0, u0); acc_u4(a1, u1); acc_u4(a0, u2); acc_u4(a1, u3);
    }
    for (; j < c; ++j) {
        const int s = __builtin_nontemporal_load(er + j);
        uint4 u = *reinterpret_cast<const uint4*>(base + (size_t)s * HID_DIM);
        acc_u4(a0, u);
    }

    uint4 o;
    o.x = pack2((a0[0] + a1[0]) * r, (a0[1] + a1[1]) * r);
    o.y = pack2((a0[2] + a1[2]) * r, (a0[3] + a1[3]) * r);
    o.z = pack2((a0[4] + a1[4]) * r, (a0[5] + a1[5]) * r);
    o.w = pack2((a0[6] + a1[6]) * r, (a0[7] + a1[7]) * r);
    *reinterpret_cast<uint4*>(Mb + (size_t)node * HID_DIM + lane * 8) = o;
}

// ---------------------------------------------------------------------------
// K5: fused layer-2 GEMM + output GEMM.
//     Phase 1: h2 = relu(m2b @ wp2 + b2) masked -> LDS (bf16, stride 136)
//     Phase 2: out = h2 @ wpo + bout (fp32).  A-row loads nontemporal.
// ---------------------------------------------------------------------------
#define H2S (HID_DIM + 8)
__global__ __launch_bounds__(256) void k_mgemm23(const unsigned short* __restrict__ A,
                                                 const unsigned short* __restrict__ Wp2g,
                                                 const unsigned short* __restrict__ Wpog,
                                                 const float* __restrict__ b2,
                                                 const float* __restrict__ bout,
                                                 const int* __restrict__ cnt,
                                                 float* __restrict__ out) {
    __shared__ unsigned short Wp2s[HID_DIM * HID_DIM];   // 32 KB
    __shared__ unsigned short Wpos[HID_DIM * OUT_DIM];   //  8 KB
    __shared__ unsigned short h2s[64 * H2S];             // 17 KB
    const int tid = threadIdx.x;
#pragma unroll
    for (int f = tid; f < HID_DIM * HID_DIM / 8; f += 256)
        reinterpret_cast<uint4*>(Wp2s)[f] = reinterpret_cast<const uint4*>(Wp2g)[f];
#pragma unroll
    for (int f = tid; f < HID_DIM * OUT_DIM / 8; f += 256)
        reinterpret_cast<uint4*>(Wpos)[f] = reinterpret_cast<const uint4*>(Wpog)[f];
    __syncthreads();

    const int w  = tid >> 6;
    const int l  = tid & 63;
    const int lr = l & 15;
    const int lg = l >> 4;
    const int row = blockIdx.x * 64 + w * 16 + lr;
    const bool rok = row < N_NODES;
    const unsigned short* Arow = A + (size_t)row * HID_DIM;

    fx4_t acc[8];
#pragma unroll
    for (int ct = 0; ct < 8; ++ct) acc[ct] = (fx4_t){0.f, 0.f, 0.f, 0.f};

#pragma unroll
    for (int kc = 0; kc < HID_DIM; kc += 32) {
        bh8_t af = {};
        if (rok) af = __builtin_nontemporal_load(
            reinterpret_cast<const bh8_t*>(Arow + kc + lg * 8));
#pragma unroll
        for (int ct = 0; ct < 8; ++ct) {
            const bh8_t bf = *reinterpret_cast<const bh8_t*>(
                &Wp2s[(((kc >> 3) + lg) * HID_DIM + ct * 16 + lr) * 8]);
            acc[ct] = __builtin_amdgcn_mfma_f32_16x16x32_bf16(af, bf, acc[ct], 0, 0, 0);
        }
    }

    const int lrow0 = w * 16 + lg * 4;
    const int orow0 = blockIdx.x * 64 + lrow0;
    bool on[4];
#pragma unroll
    for (int r = 0; r < 4; ++r)
        on[r] = (orow0 + r < N_NODES) && (cnt[orow0 + r] > 0);

#pragma unroll
    for (int ct = 0; ct < 8; ++ct) {
        const int m = ct * 16 + lr;
        const float bm = b2[m];
#pragma unroll
        for (int r = 0; r < 4; ++r) {
            float v = on[r] ? fmaxf(acc[ct][r] + bm, 0.f) : 0.f;
            h2s[(lrow0 + r) * H2S + m] = f2bf(v);
        }
    }
    __syncthreads();

    fx4_t acc2[2];
#pragma unroll
    for (int ct = 0; ct < 2; ++ct) acc2[ct] = (fx4_t){0.f, 0.f, 0.f, 0.f};

#pragma unroll
    for (int kc = 0; kc < HID_DIM; kc += 32) {
        const bh8_t af = *reinterpret_cast<const bh8_t*>(
            &h2s[(w * 16 + lr) * H2S + kc + lg * 8]);
#pragma unroll
        for (int ct = 0; ct < 2; ++ct) {
            const bh8_t bf = *reinterpret_cast<const bh8_t*>(
                &Wpos[(((kc >> 3) + lg) * OUT_DIM + ct * 16 + lr) * 8]);
            acc2[ct] = __builtin_amdgcn_mfma_f32_16x16x32_bf16(af, bf, acc2[ct], 0, 0, 0);
        }
    }

#pragma unroll
    for (int ct = 0; ct < 2; ++ct) {
        const int m = ct * 16 + lr;
        const float bm = bout[m];
#pragma unroll
        for (int r = 0; r < 4; ++r) {
            const int n = orow0 + r;
            if (n < N_NODES)
                out[(size_t)n * OUT_DIM + m] = acc2[ct][r] + bm;
        }
    }
}

// ---------------------------------------------------------------------------
extern "C" void kernel_launch(void* const* d_in, const int* in_sizes, int n_in,
                              void* d_out, int out_size, void* d_ws, size_t ws_size,
                              hipStream_t stream) {
    const float* x    = (const float*)d_in[0];
    const int*   ei   = (const int*)d_in[1];
    const float* W1   = (const float*)d_in[2];
    const float* b1   = (const float*)d_in[3];
    const float* W2   = (const float*)d_in[4];
    const float* b2   = (const float*)d_in[5];
    const float* Wout = (const float*)d_in[6];
    const float* bout = (const float*)d_in[7];
    float* out = (float*)d_out;

    const int* src = ei;
    const int* dst = ei + N_EDGES;

    // workspace layout (16B aligned)
    char* ws = (char*)d_ws;
    int*            cnt = (int*)(ws + 0);                    //    200,000
    int*            ell = (int*)(ws + 200000);               // 12,800,000 -> 13,000,000
    unsigned short* xb  = (unsigned short*)(ws + 13000000);  //  6,400,000 -> 19,400,000
    unsigned short* h1b = (unsigned short*)(ws + 19400000);  // 12,800,000 -> 32,200,000
    unsigned short* m2b = (unsigned short*)(ws + 32200000);  // 12,800,000 -> 45,000,000
    unsigned short* m1b = (unsigned short*)(ws + 45000000);  //  6,400,000 -> 51,400,000
    unsigned short* wp1 = (unsigned short*)(ws + 51400000);  //    16,384 -> 51,416,384
    unsigned short* wp2 = (unsigned short*)(ws + 51416384);  //    32,768 -> 51,449,152
    unsigned short* wpo = (unsigned short*)(ws + 51449152);  //     8,192 -> 51,457,344

    const int GB  = (N_NODES + 63) / 64;          // 782
    const int AB1 = (N_NODES + 31) / 32;          // 1563
    const int AB2 = N_NODES / 16;                 // 3125

    // prep: cast + weight packing + cnt zeroing (all independent of scatter)
    k_prep<<<CAST_BLKS + PW1_BLKS + PW2_BLKS + PWO_BLKS + ZERO_BLKS, 256, 0, stream>>>(
        x, xb, W1, wp1, W2, wp2, Wout, wpo, cnt);

    // ELL scatter, isolated (R7 shape + nontemporal edge streams)
    k_ell<<<FILL_NJ * NRANGE, 256, 0, stream>>>(src, dst, cnt, ell);

    // layer 1: aggregate then GEMM
    k_agg1<<<AB1, 256, 0, stream>>>(xb, ell, cnt, m1b);
    k_mgemm1<<<GB, 256, 0, stream>>>(m1b, wp1, b1, cnt, h1b);

    // layer 2 aggregation
    k_agg2<<<AB2, 256, 0, stream>>>(h1b, ell, cnt, m2b);

    // fused layer-2 GEMM + output GEMM
    k_mgemm23<<<GB, 256, 0, stream>>>(m2b, wp2, wpo, b2, bout, cnt, out);
}

// Round 17
// 131.119 us; speedup vs baseline: 1.0865x; 1.0865x over previous
//
#include <hip/hip_runtime.h>
#include <hip/hip_bf16.h>

#define N_NODES 50000
#define N_EDGES 800000
#define IN_DIM  64
#define HID_DIM 128
#define OUT_DIM 32
#define ELLW    64    // max supported degree; P(max_deg>64) ~ 1e-13 for this graph

#define NRANGE   8
#define RNG      (N_NODES / NRANGE)                      // 6250
#define FILL_CH  2048
#define FILL_NJ  ((N_EDGES + FILL_CH - 1) / FILL_CH)     // 391

#define CAST_BLKS 3125   // 800000 float4 / 256
#define PW1_BLKS  32     // 64*128/256
#define PW2_BLKS  64     // 128*128/256
#define PWO_BLKS  16     // 128*32/256
#define ZERO_BLKS 49     // 49*1024 >= 50000 ints

typedef short bh8_t  __attribute__((ext_vector_type(8)));   // 8 bf16 (4 VGPRs)
typedef float fx4_t  __attribute__((ext_vector_type(4)));   // MFMA acc

// bf16 helpers (raw-bit, header-version independent)
__device__ inline float bflo(unsigned int u) {
    union { unsigned int i; float f; } c; c.i = u << 16; return c.f;
}
__device__ inline float bfhi(unsigned int u) {
    union { unsigned int i; float f; } c; c.i = u & 0xffff0000u; return c.f;
}
__device__ inline unsigned short f2bf(float f) {   // round-to-nearest-even
    union { float f; unsigned int i; } c; c.f = f;
    unsigned int u = c.i;
    u += 0x7fffu + ((u >> 16) & 1u);
    return (unsigned short)(u >> 16);
}
__device__ inline unsigned int pack2(float a, float b) {
    return (unsigned int)f2bf(a) | ((unsigned int)f2bf(b) << 16);
}
__device__ inline void acc_u2(float* a, uint2 u) {
    a[0] += bflo(u.x); a[1] += bfhi(u.x);
    a[2] += bflo(u.y); a[3] += bfhi(u.y);
}
__device__ inline void acc_u4(float* a, uint4 u) {
    a[0] += bflo(u.x); a[1] += bfhi(u.x);
    a[2] += bflo(u.y); a[3] += bfhi(u.y);
    a[4] += bflo(u.z); a[5] += bfhi(u.z);
    a[6] += bflo(u.w); a[7] += bfhi(u.w);
}

template <int K, int M>
__device__ inline void packw_one(const float* __restrict__ W,
                                 unsigned short* __restrict__ Wp, int f) {
    const int k = f / M, m = f % M;
    Wp[((k >> 3) * M + m) * 8 + (k & 7)] = f2bf(W[f]);
}

// ---------------------------------------------------------------------------
// K0: prep — cast x -> bf16, pack W1/W2/Wout, zero cnt.  Runs BEFORE the
//     scatter (separate kernel): co-scheduling the 19MB cast stream with the
//     scatter evicts the scatter's L2-resident ELL lines (R9's k_pe showed
//     WRITE 37.8MB vs ideal 19MB) — keep them apart.  [R16: nt hints on the
//     cast were part of a net regression — plain cached accesses.]
// ---------------------------------------------------------------------------
__global__ void k_prep(const float* __restrict__ x, unsigned short* __restrict__ xb,
                       const float* __restrict__ W1, unsigned short* __restrict__ wp1,
                       const float* __restrict__ W2, unsigned short* __restrict__ wp2,
                       const float* __restrict__ Wout, unsigned short* __restrict__ wpo,
                       int* __restrict__ cnt) {
    const int bid = blockIdx.x;
    if (bid < CAST_BLKS) {
        const int i = bid * 256 + threadIdx.x;            // exactly 800000 float4s
        float4 v = reinterpret_cast<const float4*>(x)[i];
        ushort4 o;
        o.x = f2bf(v.x); o.y = f2bf(v.y); o.z = f2bf(v.z); o.w = f2bf(v.w);
        reinterpret_cast<ushort4*>(xb)[i] = o;
    } else if (bid < CAST_BLKS + PW1_BLKS) {
        packw_one<IN_DIM, HID_DIM>(W1, wp1, (bid - CAST_BLKS) * 256 + threadIdx.x);
    } else if (bid < CAST_BLKS + PW1_BLKS + PW2_BLKS) {
        packw_one<HID_DIM, HID_DIM>(W2, wp2, (bid - CAST_BLKS - PW1_BLKS) * 256 + threadIdx.x);
    } else if (bid < CAST_BLKS + PW1_BLKS + PW2_BLKS + PWO_BLKS) {
        packw_one<HID_DIM, OUT_DIM>(Wout, wpo,
                                    (bid - CAST_BLKS - PW1_BLKS - PW2_BLKS) * 256 + threadIdx.x);
    } else {
        const int zb = bid - (CAST_BLKS + PW1_BLKS + PW2_BLKS + PWO_BLKS);
#pragma unroll
        for (int k2 = 0; k2 < 4; ++k2) {
            const int i = zb * 1024 + k2 * 256 + threadIdx.x;
            if (i < N_NODES) cnt[i] = 0;
        }
    }
}

// ---------------------------------------------------------------------------
// K1: single-pass ELL build, dst-range x XCD partitioned (round-7 champion
//     version: 2048-edge chunks, 8 iterations/block).  r = blockIdx&7 owns
//     dst range [r*6250,(r+1)*6250) and round-robins to one XCD, so each
//     node's 256B ELL row is written by ONE XCD while its 1.6MB range slice
//     is L2-resident.  8x redundant dst reads (~25MB) are L2/L3-served —
//     and MUST stay cached (R16's nontemporal hint on dst/src regressed).
// ---------------------------------------------------------------------------
__global__ __launch_bounds__(256) void k_ell(const int* __restrict__ src,
                                             const int* __restrict__ dst,
                                             int* __restrict__ cnt,
                                             int* __restrict__ ell) {
    const int r    = blockIdx.x & (NRANGE - 1);
    const int j    = blockIdx.x >> 3;
    const int lo   = r * RNG;
    const int base = j * FILL_CH;
#pragma unroll
    for (int i = 0; i < FILL_CH / 256; ++i) {
        const int e = base + i * 256 + threadIdx.x;
        if (e < N_EDGES) {
            const int d = dst[e];
            if ((unsigned)(d - lo) < (unsigned)RNG) {
                const int p = atomicAdd(&cnt[d], 1);
                if (p < ELLW) ell[(size_t)d * ELLW + p] = src[e];
            }
        }
    }
}

// ---------------------------------------------------------------------------
// K2: layer-1 aggregation (64-dim) over ELL; 16 lanes/node, 8-edge pipeline.
//     m1b = bf16(mean of neighbor xb rows), fp32 acc.  [Split from the GEMM:
//     the fused version (R7/R8 k_ag1, 4 threads/node) was 41µs latency-bound;
//     16 lanes/node restores 4x memory-level parallelism.]
// ---------------------------------------------------------------------------
__global__ __launch_bounds__(256) void k_agg1(const unsigned short* __restrict__ Xb,
                                              const int* __restrict__ ell,
                                              const int* __restrict__ cnt,
                                              unsigned short* __restrict__ Mb) {
    const int gid  = threadIdx.x >> 4;
    const int lane = threadIdx.x & 15;
    const int node = blockIdx.x * 16 + gid;     // grid 3125*16 = 50000 exact
    const int c = min(cnt[node], ELLW);
    const float r = (c > 0) ? 1.0f / (float)c : 0.0f;
    const int* er = ell + (size_t)node * ELLW;
    const unsigned short* base = Xb + lane * 4;

    float a0[4], a1[4];
#pragma unroll
    for (int v = 0; v < 4; ++v) { a0[v] = 0.f; a1[v] = 0.f; }

    int j = 0;
    for (; j + 8 <= c; j += 8) {
        const int4 e03 = *reinterpret_cast<const int4*>(er + j);
        const int4 e47 = *reinterpret_cast<const int4*>(er + j + 4);
        uint2 u0 = *reinterpret_cast<const uint2*>(base + (size_t)e03.x * IN_DIM);
        uint2 u1 = *reinterpret_cast<const uint2*>(base + (size_t)e03.y * IN_DIM);
        uint2 u2 = *reinterpret_cast<const uint2*>(base + (size_t)e03.z * IN_DIM);
        uint2 u3 = *reinterpret_cast<const uint2*>(base + (size_t)e03.w * IN_DIM);
        uint2 u4 = *reinterpret_cast<const uint2*>(base + (size_t)e47.x * IN_DIM);
        uint2 u5 = *reinterpret_cast<const uint2*>(base + (size_t)e47.y * IN_DIM);
        uint2 u6 = *reinterpret_cast<const uint2*>(base + (size_t)e47.z * IN_DIM);
        uint2 u7 = *reinterpret_cast<const uint2*>(base + (size_t)e47.w * IN_DIM);
        acc_u2(a0, u0); acc_u2(a1, u1); acc_u2(a0, u2); acc_u2(a1, u3);
        acc_u2(a0, u4); acc_u2(a1, u5); acc_u2(a0, u6); acc_u2(a1, u7);
    }
    for (; j + 4 <= c; j += 4) {
        const int4 e4 = *reinterpret_cast<const int4*>(er + j);
        uint2 u0 = *reinterpret_cast<const uint2*>(base + (size_t)e4.x * IN_DIM);
        uint2 u1 = *reinterpret_cast<const uint2*>(base + (size_t)e4.y * IN_DIM);
        uint2 u2 = *reinterpret_cast<const uint2*>(base + (size_t)e4.z * IN_DIM);
        uint2 u3 = *reinterpret_cast<const uint2*>(base + (size_t)e4.w * IN_DIM);
        acc_u2(a0, u0); acc_u2(a1, u1); acc_u2(a0, u2); acc_u2(a1, u3);
    }
    for (; j < c; ++j) {
        uint2 u = *reinterpret_cast<const uint2*>(base + (size_t)er[j] * IN_DIM);
        acc_u2(a0, u);
    }

    uint2 o;
    o.x = pack2((a0[0] + a1[0]) * r, (a0[1] + a1[1]) * r);
    o.y = pack2((a0[2] + a1[2]) * r, (a0[3] + a1[3]) * r);
    *reinterpret_cast<uint2*>(Mb + (size_t)node * IN_DIM + lane * 4) = o;
}

// ---------------------------------------------------------------------------
// K3: layer-1 MFMA GEMM.  h1b = bf16(relu(m1b @ wp1 + b1)), masked by cnt.
// ---------------------------------------------------------------------------
__global__ __launch_bounds__(256) void k_mgemm1(const unsigned short* __restrict__ A,
                                                const unsigned short* __restrict__ Wpg,
                                                const float* __restrict__ b1,
                                                const int* __restrict__ cnt,
                                                unsigned short* __restrict__ h1b) {
    __shared__ unsigned short Wp[IN_DIM * HID_DIM];   // 16 KB
    const int tid = threadIdx.x;
#pragma unroll
    for (int f = tid; f < IN_DIM * HID_DIM / 8; f += 256)
        reinterpret_cast<uint4*>(Wp)[f] = reinterpret_cast<const uint4*>(Wpg)[f];
    __syncthreads();

    const int w  = tid >> 6;
    const int l  = tid & 63;
    const int lr = l & 15;
    const int lg = l >> 4;
    const int row = blockIdx.x * 64 + w * 16 + lr;
    const bool rok = row < N_NODES;
    const unsigned short* Arow = A + (size_t)row * IN_DIM;

    fx4_t acc[8];
#pragma unroll
    for (int ct = 0; ct < 8; ++ct) acc[ct] = (fx4_t){0.f, 0.f, 0.f, 0.f};

#pragma unroll
    for (int kc = 0; kc < IN_DIM; kc += 32) {
        bh8_t af = {};
        if (rok) af = *reinterpret_cast<const bh8_t*>(Arow + kc + lg * 8);
#pragma unroll
        for (int ct = 0; ct < 8; ++ct) {
            const bh8_t bf = *reinterpret_cast<const bh8_t*>(
                &Wp[(((kc >> 3) + lg) * HID_DIM + ct * 16 + lr) * 8]);
            acc[ct] = __builtin_amdgcn_mfma_f32_16x16x32_bf16(af, bf, acc[ct], 0, 0, 0);
        }
    }

    const int orow0 = blockIdx.x * 64 + w * 16 + lg * 4;
    bool on[4];
#pragma unroll
    for (int r = 0; r < 4; ++r)
        on[r] = (orow0 + r < N_NODES) && (cnt[orow0 + r] > 0);

#pragma unroll
    for (int ct = 0; ct < 8; ++ct) {
        const int m = ct * 16 + lr;
        const float bm = b1[m];
#pragma unroll
        for (int r = 0; r < 4; ++r) {
            const int n = orow0 + r;
            if (n < N_NODES) {
                float v = on[r] ? fmaxf(acc[ct][r] + bm, 0.f) : 0.f;
                h1b[(size_t)n * HID_DIM + m] = f2bf(v);
            }
        }
    }
}

// ---------------------------------------------------------------------------
// K4: layer-2 aggregation (128-dim) over ELL; 16 lanes/node, 8-edge pipeline.
// ---------------------------------------------------------------------------
__global__ __launch_bounds__(256) void k_agg2(const unsigned short* __restrict__ Xb,
                                              const int* __restrict__ ell,
                                              const int* __restrict__ cnt,
                                              unsigned short* __restrict__ Mb) {
    const int gid  = threadIdx.x >> 4;
    const int lane = threadIdx.x & 15;
    const int node = blockIdx.x * 16 + gid;     // grid 3125*16 = 50000 exact
    const int c = min(cnt[node], ELLW);
    const float r = (c > 0) ? 1.0f / (float)c : 0.0f;
    const int* er = ell + (size_t)node * ELLW;
    const unsigned short* base = Xb + lane * 8;

    float a0[8], a1[8];
#pragma unroll
    for (int v = 0; v < 8; ++v) { a0[v] = 0.f; a1[v] = 0.f; }

    int j = 0;
    for (; j + 8 <= c; j += 8) {
        const int4 e03 = *reinterpret_cast<const int4*>(er + j);
        const int4 e47 = *reinterpret_cast<const int4*>(er + j + 4);
        uint4 u0 = *reinterpret_cast<const uint4*>(base + (size_t)e03.x * HID_DIM);
        uint4 u1 = *reinterpret_cast<const uint4*>(base + (size_t)e03.y * HID_DIM);
        uint4 u2 = *reinterpret_cast<const uint4*>(base + (size_t)e03.z * HID_DIM);
        uint4 u3 = *reinterpret_cast<const uint4*>(base + (size_t)e03.w * HID_DIM);
        uint4 u4 = *reinterpret_cast<const uint4*>(base + (size_t)e47.x * HID_DIM);
        uint4 u5 = *reinterpret_cast<const uint4*>(base + (size_t)e47.y * HID_DIM);
        uint4 u6 = *reinterpret_cast<const uint4*>(base + (size_t)e47.z * HID_DIM);
        uint4 u7 = *reinterpret_cast<const uint4*>(base + (size_t)e47.w * HID_DIM);
        acc_u4(a0, u0); acc_u4(a1, u1); acc_u4(a0, u2); acc_u4(a1, u3);
        acc_u4(a0, u4); acc_u4(a1, u5); acc_u4(a0, u6); acc_u4(a1, u7);
    }
    for (; j + 4 <= c; j += 4) {
        const int4 e4 = *reinterpret_cast<const int4*>(er + j);
        uint4 u0 = *reinterpret_cast<const uint4*>(base + (size_t)e4.x * HID_DIM);
        uint4 u1 = *reinterpret_cast<const uint4*>(base + (size_t)e4.y * HID_DIM);
        uint4 u2 = *reinterpret_cast<const uint4*>(base + (size_t)e4.z * HID_DIM);
        uint4 u3 = *reinterpret_cast<const uint4*>(base + (size_t)e4.w * HID_DIM);
        acc_u4(a0, u0); acc_u4(a1, u1); acc_u4(a0, u2); acc_u4(a1, u3);
    }
    for (; j < c; ++j) {
        uint4 u = *reinterpret_cast<const uint4*>(base + (size_t)er[j] * HID_DIM);
        acc_u4(a0, u);
    }

    uint4 o;
    o.x = pack2((a0[0] + a1[0]) * r, (a0[1] + a1[1]) * r);
    o.y = pack2((a0[2] + a1[2]) * r, (a0[3] + a1[3]) * r);
    o.z = pack2((a0[4] + a1[4]) * r, (a0[5] + a1[5]) * r);
    o.w = pack2((a0[6] + a1[6]) * r, (a0[7] + a1[7]) * r);
    *reinterpret_cast<uint4*>(Mb + (size_t)node * HID_DIM + lane * 8) = o;
}

// ---------------------------------------------------------------------------
// K5: fused layer-2 GEMM + output GEMM.
//     Phase 1: h2 = relu(m2b @ wp2 + b2) masked -> LDS (bf16, stride 136)
//     Phase 2: out = h2 @ wpo + bout (fp32)
// ---------------------------------------------------------------------------
#define H2S (HID_DIM + 8)
__global__ __launch_bounds__(256) void k_mgemm23(const unsigned short* __restrict__ A,
                                                 const unsigned short* __restrict__ Wp2g,
                                                 const unsigned short* __restrict__ Wpog,
                                                 const float* __restrict__ b2,
                                                 const float* __restrict__ bout,
                                                 const int* __restrict__ cnt,
                                                 float* __restrict__ out) {
    __shared__ unsigned short Wp2s[HID_DIM * HID_DIM];   // 32 KB
    __shared__ unsigned short Wpos[HID_DIM * OUT_DIM];   //  8 KB
    __shared__ unsigned short h2s[64 * H2S];             // 17 KB
    const int tid = threadIdx.x;
#pragma unroll
    for (int f = tid; f < HID_DIM * HID_DIM / 8; f += 256)
        reinterpret_cast<uint4*>(Wp2s)[f] = reinterpret_cast<const uint4*>(Wp2g)[f];
#pragma unroll
    for (int f = tid; f < HID_DIM * OUT_DIM / 8; f += 256)
        reinterpret_cast<uint4*>(Wpos)[f] = reinterpret_cast<const uint4*>(Wpog)[f];
    __syncthreads();

    const int w  = tid >> 6;
    const int l  = tid & 63;
    const int lr = l & 15;
    const int lg = l >> 4;
    const int row = blockIdx.x * 64 + w * 16 + lr;
    const bool rok = row < N_NODES;
    const unsigned short* Arow = A + (size_t)row * HID_DIM;

    fx4_t acc[8];
#pragma unroll
    for (int ct = 0; ct < 8; ++ct) acc[ct] = (fx4_t){0.f, 0.f, 0.f, 0.f};

#pragma unroll
    for (int kc = 0; kc < HID_DIM; kc += 32) {
        bh8_t af = {};
        if (rok) af = *reinterpret_cast<const bh8_t*>(Arow + kc + lg * 8);
#pragma unroll
        for (int ct = 0; ct < 8; ++ct) {
            const bh8_t bf = *reinterpret_cast<const bh8_t*>(
                &Wp2s[(((kc >> 3) + lg) * HID_DIM + ct * 16 + lr) * 8]);
            acc[ct] = __builtin_amdgcn_mfma_f32_16x16x32_bf16(af, bf, acc[ct], 0, 0, 0);
        }
    }

    const int lrow0 = w * 16 + lg * 4;
    const int orow0 = blockIdx.x * 64 + lrow0;
    bool on[4];
#pragma unroll
    for (int r = 0; r < 4; ++r)
        on[r] = (orow0 + r < N_NODES) && (cnt[orow0 + r] > 0);

#pragma unroll
    for (int ct = 0; ct < 8; ++ct) {
        const int m = ct * 16 + lr;
        const float bm = b2[m];
#pragma unroll
        for (int r = 0; r < 4; ++r) {
            float v = on[r] ? fmaxf(acc[ct][r] + bm, 0.f) : 0.f;
            h2s[(lrow0 + r) * H2S + m] = f2bf(v);
        }
    }
    __syncthreads();

    fx4_t acc2[2];
#pragma unroll
    for (int ct = 0; ct < 2; ++ct) acc2[ct] = (fx4_t){0.f, 0.f, 0.f, 0.f};

#pragma unroll
    for (int kc = 0; kc < HID_DIM; kc += 32) {
        const bh8_t af = *reinterpret_cast<const bh8_t*>(
            &h2s[(w * 16 + lr) * H2S + kc + lg * 8]);
#pragma unroll
        for (int ct = 0; ct < 2; ++ct) {
            const bh8_t bf = *reinterpret_cast<const bh8_t*>(
                &Wpos[(((kc >> 3) + lg) * OUT_DIM + ct * 16 + lr) * 8]);
            acc2[ct] = __builtin_amdgcn_mfma_f32_16x16x32_bf16(af, bf, acc2[ct], 0, 0, 0);
        }
    }

#pragma unroll
    for (int ct = 0; ct < 2; ++ct) {
        const int m = ct * 16 + lr;
        const float bm = bout[m];
#pragma unroll
        for (int r = 0; r < 4; ++r) {
            const int n = orow0 + r;
            if (n < N_NODES)
                out[(size_t)n * OUT_DIM + m] = acc2[ct][r] + bm;
        }
    }
}

// ---------------------------------------------------------------------------
extern "C" void kernel_launch(void* const* d_in, const int* in_sizes, int n_in,
                              void* d_out, int out_size, void* d_ws, size_t ws_size,
                              hipStream_t stream) {
    const float* x    = (const float*)d_in[0];
    const int*   ei   = (const int*)d_in[1];
    const float* W1   = (const float*)d_in[2];
    const float* b1   = (const float*)d_in[3];
    const float* W2   = (const float*)d_in[4];
    const float* b2   = (const float*)d_in[5];
    const float* Wout = (const float*)d_in[6];
    const float* bout = (const float*)d_in[7];
    float* out = (float*)d_out;

    const int* src = ei;
    const int* dst = ei + N_EDGES;

    // workspace layout (16B aligned)
    char* ws = (char*)d_ws;
    int*            cnt = (int*)(ws + 0);                    //    200,000
    int*            ell = (int*)(ws + 200000);               // 12,800,000 -> 13,000,000
    unsigned short* xb  = (unsigned short*)(ws + 13000000);  //  6,400,000 -> 19,400,000
    unsigned short* h1b = (unsigned short*)(ws + 19400000);  // 12,800,000 -> 32,200,000
    unsigned short* m2b = (unsigned short*)(ws + 32200000);  // 12,800,000 -> 45,000,000
    unsigned short* m1b = (unsigned short*)(ws + 45000000);  //  6,400,000 -> 51,400,000
    unsigned short* wp1 = (unsigned short*)(ws + 51400000);  //    16,384 -> 51,416,384
    unsigned short* wp2 = (unsigned short*)(ws + 51416384);  //    32,768 -> 51,449,152
    unsigned short* wpo = (unsigned short*)(ws + 51449152);  //     8,192 -> 51,457,344

    const int GB = (N_NODES + 63) / 64;          // 782
    const int AB = N_NODES / 16;                 // 3125

    // prep: cast + weight packing + cnt zeroing (all independent of scatter)
    k_prep<<<CAST_BLKS + PW1_BLKS + PW2_BLKS + PWO_BLKS + ZERO_BLKS, 256, 0, stream>>>(
        x, xb, W1, wp1, W2, wp2, Wout, wpo, cnt);

    // ELL scatter, isolated (round-7 champion variant)
    k_ell<<<FILL_NJ * NRANGE, 256, 0, stream>>>(src, dst, cnt, ell);

    // layer 1: aggregate then GEMM (split — fused version was latency-bound)
    k_agg1<<<AB, 256, 0, stream>>>(xb, ell, cnt, m1b);
    k_mgemm1<<<GB, 256, 0, stream>>>(m1b, wp1, b1, cnt, h1b);

    // layer 2 aggregation
    k_agg2<<<AB, 256, 0, stream>>>(h1b, ell, cnt, m2b);

    // fused layer-2 GEMM + output GEMM
    k_mgemm23<<<GB, 256, 0, stream>>>(m2b, wp2, wpo, b2, bout, cnt, out);
}